// Round 8
// baseline (310.939 us; speedup 1.0000x reference)
//
#include <hip/hip_runtime.h>

#define N_ANCHORS 5000
#define N_CLASSES 80
#define OUT_COLS  (N_CLASSES + 4)   // 84
#define MAX_BOXES 300
#define SCORE_THR 0.05f

#define NB        4096               // score buckets per class
#define SORT_PAD  5056
#define BLOCK     512
#define CPT       10                 // entries per thread (10*512=5120>=5000)

typedef unsigned long long u64;
typedef unsigned int u32;

__device__ __forceinline__ float readlane_f(float v, int l) {
    return __int_as_float(__builtin_amdgcn_readlane(__float_as_int(v), l));
}
// monotone score->bucket map (affects load balance only, never exactness)
__device__ __forceinline__ int bucket_of(float s) {
    float u = sqrtf(s);
    int b = (int)((u - 0.2236f) * 5275.0f);
    return min(max(b, 0), NB - 1);
}

// ================= 1) prep: coalesced out init + cls transpose =================
#define INIT_BLKS 1641               // ceil(5000*84/256)
#define TR_BX     157                // ceil(5000/32)
#define TR_BY     3                  // ceil(80/32)
#define TR_BLKS   (TR_BX * TR_BY)

__global__ __launch_bounds__(256) void prep(const float* __restrict__ boxes,
                                            const float* __restrict__ cls,
                                            float* __restrict__ clsT,
                                            float* __restrict__ out) {
    __shared__ float tile[32][33];
    int b = blockIdx.x;
    if (b < INIT_BLKS) {                         // ---- init out (coalesced) ----
        int i = b * 256 + threadIdx.x;
        if (i < N_ANCHORS * OUT_COLS) {
            int row = i / OUT_COLS, col = i - row * OUT_COLS;
            out[i] = (col < 4) ? boxes[row * 4 + col] : 0.0f;
        }
        return;
    }
    b -= INIT_BLKS;                              // ---- transpose cls -> clsT ----
    int bx_ = b % TR_BX, by_ = b / TR_BX;
    int j0 = bx_ * 32, c0 = by_ * 32;
    int tx = threadIdx.x & 31, ty = threadIdx.x >> 5;
    #pragma unroll
    for (int r = 0; r < 32; r += 8) {
        int j = j0 + ty + r, c = c0 + tx;
        tile[ty + r][tx] = (j < N_ANCHORS && c < N_CLASSES) ? cls[j * N_CLASSES + c] : 0.0f;
    }
    __syncthreads();
    #pragma unroll
    for (int r = 0; r < 32; r += 8) {
        int c = c0 + ty + r, j = j0 + tx;
        if (c < N_CLASSES && j < N_ANCHORS) clsT[(size_t)c * N_ANCHORS + j] = tile[tx][ty + r];
    }
}

// ================= 2) per-class: bucket sort + compaction-pass NMS (no mask) =================
__global__ __launch_bounds__(BLOCK, 1) void sort_scan(const float* __restrict__ clsT,
                                                      const float4* __restrict__ boxes4,
                                                      float* __restrict__ out) {
    __shared__ u64 lk[SORT_PAD];        // 40448 B sorted keys (score desc, idx asc)
    __shared__ u32 hist[NB];            // 16384 B
    __shared__ u32 wtot[8];
    __shared__ float4 kbox[64];         // this pass's kept boxes
    __shared__ u32 misc[2];             // kept total, nk this pass

    const int c = blockIdx.x;
    const int t = threadIdx.x;
    const int lane = t & 63;
    const int wave = t >> 6;

    // ---- load scores (coalesced from clsT) ----
    u32 sb[CPT];
    #pragma unroll
    for (int m = 0; m < CPT; ++m) {
        int j = t + m * BLOCK;
        sb[m] = 0u;
        if (j < N_ANCHORS) {
            float s = clsT[(size_t)c * N_ANCHORS + j];
            if (s > SCORE_THR) sb[m] = __float_as_uint(s);
        }
    }
    for (int b = t; b < NB; b += BLOCK) hist[b] = 0u;
    __syncthreads();
    #pragma unroll
    for (int m = 0; m < CPT; ++m)
        if (sb[m]) atomicAdd(&hist[bucket_of(__uint_as_float(sb[m]))], 1u);
    __syncthreads();

    // exclusive prefix: thread owns 8 consecutive buckets
    const int hbase = t * 8;
    u32 vals[8]; u32 run = 0;
    #pragma unroll
    for (int k = 0; k < 8; ++k) { run += hist[hbase + k]; vals[k] = run; }
    u32 x = run;
    #pragma unroll
    for (int off = 1; off < 64; off <<= 1) { u32 y = __shfl_up(x, off); if (lane >= off) x += y; }
    if (lane == 63) wtot[wave] = x;
    __syncthreads();
    u32 woff = 0;
    for (int w = 0; w < wave; ++w) woff += wtot[w];
    const u32 exb = woff + x - run;
    #pragma unroll
    for (int k = 0; k < 8; ++k) hist[hbase + k] = exb + (k ? vals[k - 1] : 0u);
    __syncthreads();
    #pragma unroll
    for (int m = 0; m < CPT; ++m) {
        if (sb[m]) {
            int j = t + m * BLOCK;
            u32 pos = atomicAdd(&hist[bucket_of(__uint_as_float(sb[m]))], 1u);
            lk[pos] = ((u64)sb[m] << 32) | (u32)(~(u32)j);
        }
    }
    __syncthreads();                   // hist[b] now end of bucket b
    const int total = (int)hist[NB - 1];
    for (int b = hbase; b < hbase + 8; ++b) {   // exact sort within buckets
        int s0 = b ? (int)hist[b - 1] : 0;
        int e  = (int)hist[b];
        for (int i = s0 + 1; i < e; ++i) {
            u64 key = lk[i]; int q = i - 1;
            while (q >= s0 && lk[q] < key) { lk[q + 1] = lk[q]; --q; }
            lk[q + 1] = key;
        }
    }
    __syncthreads();

    // ---- compaction passes ----
    int nlive = total;
    int kept = 0;
    while (nlive > 0) {
        const int m = min(nlive, 64);
        if (wave == 0) {
            u64 key = (lane < m) ? lk[lane] : 0ull;
            bool valid = (key != 0ull);
            u32 j = valid ? ~(u32)key : 0u;
            float sc = __uint_as_float((u32)(key >> 32));
            float4 bx = boxes4[j];
            float ar = (bx.z - bx.x) * (bx.w - bx.y);
            bool alive = valid;                   // pre-filtered by compaction
            u64 rem = __ballot(alive);
            u64 km = 0ull;
            while (rem) {                         // pure-ALU serial keep chain
                int pos = __ffsll((long long)rem) - 1;
                km |= 1ull << pos;
                ++kept;
                if (kept == MAX_BOXES) break;
                float kx1 = readlane_f(bx.x, pos);
                float ky1 = readlane_f(bx.y, pos);
                float kx2 = readlane_f(bx.z, pos);
                float ky2 = readlane_f(bx.w, pos);
                float sAB = (kx2 - kx1) * (ky2 - ky1) + ar;
                float iw = fmaxf(fminf(kx2, bx.z) - fmaxf(kx1, bx.x), 0.0f);
                float ih = fmaxf(fminf(ky2, bx.w) - fmaxf(ky1, bx.y), 0.0f);
                alive = alive && !(3.0f * (iw * ih) > sAB);   // IoU>0.5 (kills pos itself)
                rem = __ballot(alive);
            }
            if ((km >> lane) & 1ull) {
                out[(size_t)j * OUT_COLS + 4 + c] = sc;
                kbox[__popcll(km & ((1ull << lane) - 1ull))] = bx;
            }
            if (lane == 0) { misc[0] = (u32)kept; misc[1] = (u32)__popcll(km); }
        }
        __syncthreads();               // B0: misc/kbox visible
        kept = (int)misc[0];
        const int nk = (int)misc[1];
        const int rest = nlive - m;
        if (rest <= 0 || kept >= MAX_BOXES) break;

        // ---- compact lk[64..64+rest) vs this pass's nk kept boxes (direct IoU) ----
        u64 kk[CPT]; float4 bv[CPT]; float av[CPT];
        u32 am = 0u;
        #pragma unroll
        for (int i = 0; i < CPT; ++i) {
            int rel = t * CPT + i;
            if (rel < rest) {
                u64 e = lk[64 + rel];
                kk[i] = e;
                u32 j = ~(u32)e;
                float4 b4 = boxes4[j];             // L1-hot gather
                bv[i] = b4;
                av[i] = (b4.z - b4.x) * (b4.w - b4.y);
                am |= 1u << i;
            }
        }
        for (int r = 0; r < nk; ++r) {
            float4 kb = kbox[r];                    // LDS broadcast
            float kar = (kb.z - kb.x) * (kb.w - kb.y);
            #pragma unroll
            for (int i = 0; i < CPT; ++i) {
                if ((am >> i) & 1u) {
                    float iw = fmaxf(fminf(kb.z, bv[i].z) - fmaxf(kb.x, bv[i].x), 0.0f);
                    float ih = fmaxf(fminf(kb.w, bv[i].w) - fmaxf(kb.y, bv[i].y), 0.0f);
                    if (3.0f * (iw * ih) > kar + av[i]) am &= ~(1u << i);
                }
            }
        }
        int cnt = __popc(am);
        __syncthreads();               // B1: all lk reads done before overwrite

        u32 x2 = (u32)cnt;
        #pragma unroll
        for (int off = 1; off < 64; off <<= 1) { u32 y = __shfl_up(x2, off); if (lane >= off) x2 += y; }
        if (lane == 63) wtot[wave] = x2;
        __syncthreads();               // B2
        u32 wof = 0;
        for (int w = 0; w < wave; ++w) wof += wtot[w];
        u32 wp = wof + x2 - (u32)cnt;
        #pragma unroll
        for (int i = 0; i < CPT; ++i)
            if ((am >> i) & 1u) lk[wp++] = kk[i];
        int newlive = 0;
        #pragma unroll
        for (int w = 0; w < 8; ++w) newlive += (int)wtot[w];
        __syncthreads();               // B3: compacted list visible
        nlive = newlive;
    }
}

extern "C" void kernel_launch(void* const* d_in, const int* in_sizes, int n_in,
                              void* d_out, int out_size, void* d_ws, size_t ws_size,
                              hipStream_t stream) {
    const float* boxes = (const float*)d_in[0];
    const float* cls   = (const float*)d_in[1];
    float* out = (float*)d_out;
    float* clsT = (float*)d_ws;                  // 1.60 MB scratch

    prep<<<INIT_BLKS + TR_BLKS, 256, 0, stream>>>(boxes, cls, clsT, out);
    sort_scan<<<N_CLASSES, BLOCK, 0, stream>>>(clsT, (const float4*)boxes, out);
}

// Round 9
// 166.120 us; speedup vs baseline: 1.8718x; 1.8718x over previous
//
#include <hip/hip_runtime.h>

#define N_ANCHORS 5000
#define N_CLASSES 80
#define OUT_COLS  (N_CLASSES + 4)   // 84
#define MAX_BOXES 300
#define SCORE_THR 0.05f

#define NWORDS   80                  // ceil(5000/64)=79, pad to 80
#define SORT_PAD 5056
#define NCHMAX   79
#define NB       4096                // score buckets
#define RING     32                  // intra-matrix ring slots (reuses hist LDS)
#define BLOCK    512
#define CPT      10                  // 512*10 = 5120 >= 5000
#define NSCAN    80                  // scanner blocks (one per class)
#define NHELP    176                 // helper blocks (init_out + mask)
#define NSTAG    8                   // mask-row DMA staging slots

typedef unsigned long long u64;
typedef unsigned int u32;

typedef __attribute__((address_space(3))) u32 as3u32;
typedef __attribute__((address_space(1))) u32 as1u32;

__device__ __forceinline__ float readlane_f(float v, int l) {
    return __int_as_float(__builtin_amdgcn_readlane(__float_as_int(v), l));
}
__device__ __forceinline__ u64 shfl_u64(u64 v, int src) {
    int lo = __shfl((int)(u32)v, src);
    int hi = __shfl((int)(u32)(v >> 32), src);
    return ((u64)(u32)hi << 32) | (u32)lo;
}
// monotone score->bucket map (load balance only, never exactness)
__device__ __forceinline__ int bucket_of(float s) {
    float u = sqrtf(s);
    int b = (int)((u - 0.2236f) * 5275.0f);
    return min(max(b, 0), NB - 1);
}

// SMEM carve (62336 B): lk[5056]u64 @0 | ring 32*64 u64 (= hist[4096]u32) @40448 |
// flags[80]u32 @56832 | wtot[8] @57152 | misc[8] @57184 | stag[8*80]u64 @57216
__global__ __launch_bounds__(BLOCK, 1) void nms_all(const float* __restrict__ boxes,
                                                    const float4* __restrict__ boxes4,
                                                    const float* __restrict__ cls,
                                                    u64* __restrict__ mask,
                                                    u32* __restrict__ bar,
                                                    float* __restrict__ out) {
    __shared__ __align__(16) char SMEM[62336];
    const int t = threadIdx.x;
    const int lane = t & 63;
    const int wave = t >> 6;

    if (blockIdx.x >= NSCAN) {
        // ================= helper: coalesced out-init + IoU bitmask =================
        const int hb = blockIdx.x - NSCAN;
        for (int i = hb * BLOCK + t; i < N_ANCHORS * OUT_COLS; i += NHELP * BLOCK) {
            int row = i / OUT_COLS, col = i - row * OUT_COLS;
            out[i] = (col < 4) ? boxes[row * 4 + col] : 0.0f;
        }
        float4* jb = (float4*)SMEM;            // [8][64]
        float*  ja = (float*)(SMEM + 8192);
        for (int job = hb; job < 79 * 10; job += NHELP) {
            int ic = job / 10, wq = job % 10;
            int w = wq * 8 + wave;             // word 0..79
            int j = w * 64 + lane;
            float4 v = make_float4(3e8f, 3e8f, 3e8f, 3e8f);
            float aj = 0.f;
            if (j < N_ANCHORS) { v = boxes4[j]; aj = (v.z - v.x) * (v.w - v.y); }
            jb[wave * 64 + lane] = v;          // same-wave in-order LDS: no barrier
            ja[wave * 64 + lane] = aj;
            int i = ic * 64 + lane;
            if (i < N_ANCHORS) {
                float4 bi = boxes4[i];
                float ar = (bi.z - bi.x) * (bi.w - bi.y);
                u64 bits = 0ull;
                #pragma unroll 8
                for (int q = 0; q < 64; ++q) {
                    float4 bj = jb[wave * 64 + q];
                    float iw = fmaxf(fminf(bi.z, bj.z) - fmaxf(bi.x, bj.x), 0.0f);
                    float ih = fmaxf(fminf(bi.w, bj.w) - fmaxf(bi.y, bj.y), 0.0f);
                    if (3.0f * (iw * ih) > ar + ja[wave * 64 + q]) bits |= (1ull << q);
                }
                mask[(size_t)i * NWORDS + w] = bits;
            }
        }
        __syncthreads();
        if (t == 0) __hip_atomic_fetch_add(bar, 1u, __ATOMIC_RELEASE, __HIP_MEMORY_SCOPE_AGENT);
        return;
    }

    // ================= scanner block: class c =================
    const int c = blockIdx.x;
    u64* lk    = (u64*)SMEM;
    u64* ring  = (u64*)(SMEM + 40448);
    u32* hist  = (u32*)(SMEM + 40448);         // aliased: hist during sort, ring after
    u32* flags = (u32*)(SMEM + 56832);
    u32* wtot  = (u32*)(SMEM + 57152);
    u32* misc  = (u32*)(SMEM + 57184);         // 0=consumed 1=done
    u64* stag  = (u64*)(SMEM + 57216);

    // ---- load scores (column read; cls is L2/L3-resident) ----
    u32 sb[CPT];
    #pragma unroll
    for (int m = 0; m < CPT; ++m) {
        int j = t + m * BLOCK;
        sb[m] = 0u;
        if (j < N_ANCHORS) {
            float s = cls[(size_t)j * N_CLASSES + c];
            if (s > SCORE_THR) sb[m] = __float_as_uint(s);
        }
    }
    if (t < NCHMAX) flags[t] = 0u;
    if (t < 8) { wtot[t] = 0u; misc[t] = 0u; }
    for (int b = t; b < NB; b += BLOCK) hist[b] = 0u;
    __syncthreads();

    // ---- bucket histogram ----
    #pragma unroll
    for (int m = 0; m < CPT; ++m)
        if (sb[m]) atomicAdd(&hist[bucket_of(__uint_as_float(sb[m]))], 1u);
    __syncthreads();

    // ---- exclusive prefix: thread owns 8 buckets ----
    const int hbase = t * 8;
    u32 vals[8]; u32 run = 0;
    #pragma unroll
    for (int k = 0; k < 8; ++k) { run += hist[hbase + k]; vals[k] = run; }
    u32 x = run;
    #pragma unroll
    for (int off = 1; off < 64; off <<= 1) { u32 y = __shfl_up(x, off); if (lane >= off) x += y; }
    if (lane == 63) wtot[wave] = x;
    __syncthreads();
    u32 woff = 0;
    for (int w = 0; w < wave; ++w) woff += wtot[w];
    const u32 exb = woff + x - run;
    #pragma unroll
    for (int k = 0; k < 8; ++k) hist[hbase + k] = exb + (k ? vals[k - 1] : 0u);
    __syncthreads();

    // ---- scatter ----
    #pragma unroll
    for (int m = 0; m < CPT; ++m) {
        if (sb[m]) {
            int j = t + m * BLOCK;
            u32 pos = atomicAdd(&hist[bucket_of(__uint_as_float(sb[m]))], 1u);
            lk[pos] = ((u64)sb[m] << 32) | (u32)(~(u32)j);   // score desc, idx asc
        }
    }
    __syncthreads();                   // hist[b] now end of bucket b
    const int total = (int)hist[NB - 1];

    // ---- tail zero + exact insertion sort within buckets ----
    for (int v = total + t; v < SORT_PAD; v += BLOCK) lk[v] = 0ull;
    for (int b = hbase; b < hbase + 8; ++b) {
        int s0 = b ? (int)hist[b - 1] : 0;
        int e  = (int)hist[b];
        for (int i = s0 + 1; i < e; ++i) {
            u64 key = lk[i]; int q = i - 1;
            while (q >= s0 && lk[q] < key) { lk[q + 1] = lk[q]; --q; }
            lk[q + 1] = key;
        }
    }
    __syncthreads();                   // LAST barrier; waves diverge below
    const int nch = (total + 63) >> 6;

    if (wave > 0) {
        // ============ workers: intra-chunk 64x64 IoU matrices into ring ============
        for (int k = wave - 1; k < nch; k += 7) {
            for (;;) {
                if (__hip_atomic_load(&misc[1], __ATOMIC_RELAXED, __HIP_MEMORY_SCOPE_WORKGROUP)) return;
                u32 cons = __hip_atomic_load(&misc[0], __ATOMIC_RELAXED, __HIP_MEMORY_SCOPE_WORKGROUP);
                if ((int)cons + RING > k) break;
                __builtin_amdgcn_s_sleep(8);
            }
            u64 e = lk[(size_t)k * 64 + lane];
            u32 j = e ? ~(u32)e : 0u;
            float4 bx = boxes4[j];
            float ar = (bx.z - bx.x) * (bx.w - bx.y);
            u64 word = 0ull;                   // bit q: I suppress q (IoU>0.5)
            #pragma unroll 16
            for (int q = 0; q < 64; ++q) {
                float px1 = readlane_f(bx.x, q);
                float py1 = readlane_f(bx.y, q);
                float px2 = readlane_f(bx.z, q);
                float py2 = readlane_f(bx.w, q);
                float sAB = (px2 - px1) * (py2 - py1) + ar;
                float iw = fmaxf(fminf(px2, bx.z) - fmaxf(px1, bx.x), 0.0f);
                float ih = fmaxf(fminf(py2, bx.w) - fmaxf(py1, bx.y), 0.0f);
                if (3.0f * (iw * ih) > sAB) word |= (1ull << q);
            }
            ring[(size_t)(k & (RING - 1)) * 64 + lane] = word;
            if (lane == 0)
                __hip_atomic_store(&flags[k], 1u, __ATOMIC_RELEASE, __HIP_MEMORY_SCOPE_WORKGROUP);
        }
        return;
    }

    // ============ wave 0: the serial scan ============
    // wait for helpers' mask + out-init (agent scope; workers meanwhile fill ring)
    while (__hip_atomic_load(bar, __ATOMIC_ACQUIRE, __HIP_MEMORY_SCOPE_AGENT) < NHELP)
        __builtin_amdgcn_s_sleep(16);

    u64 S0 = 0ull, S1 = 0ull;          // suppressed bitmap: lane owns word lane / 64+lane
    int kept = 0, pend = 0;
    bool capped = false;

    for (int k = 0; k < nch; ++k) {
        // flush mask rows DMA'd during previous chunk (their latency was covered)
        if (pend) {
            __builtin_amdgcn_s_waitcnt(0);
            for (int r = 0; r < pend; ++r) {
                S0 |= stag[r * NWORDS + lane];
                if (lane < 16) S1 |= stag[r * NWORDS + 64 + lane];
            }
            pend = 0;
        }

        u64 key = lk[(size_t)k * 64 + lane];
        bool valid = (key != 0ull);
        u32 j = valid ? ~(u32)key : 0u;
        int W = (int)(j >> 6), bpos = (int)(j & 63u);
        float sc = __uint_as_float((u32)(key >> 32));

        // cross-chunk suppression via register bitmap
        u64 w0 = shfl_u64(S0, W & 63);
        u64 w1 = shfl_u64(S1, W & 63);
        bool alive = valid && !((((W < 64) ? w0 : w1) >> bpos) & 1ull);
        u64 rem = __ballot(alive);

        // intra matrix from workers
        while (!__hip_atomic_load(&flags[k], __ATOMIC_ACQUIRE, __HIP_MEMORY_SCOPE_WORKGROUP))
            __builtin_amdgcn_s_sleep(2);
        u64 intra = ring[(size_t)(k & (RING - 1)) * 64 + lane];

        // pure-SALU serial keep chain
        u64 km = 0ull;
        while (rem) {
            int pos = __ffsll((long long)rem) - 1;
            km |= 1ull << pos;
            if (++kept == MAX_BOXES) { capped = true; break; }
            u32 lo = (u32)__builtin_amdgcn_readlane((int)(u32)intra, pos);
            u32 hi = (u32)__builtin_amdgcn_readlane((int)(u32)(intra >> 32), pos);
            rem &= ~(((u64)hi << 32) | (u64)lo);   // self-bit clears pos
        }

        // kept lanes store their scores
        if ((km >> lane) & 1ull) out[(size_t)j * OUT_COLS + 4 + c] = sc;
        if (capped) break;

        if (lane == 0)
            __hip_atomic_store(&misc[0], (u32)(k + 1), __ATOMIC_RELEASE, __HIP_MEMORY_SCOPE_WORKGROUP);

        // batch-issue kept rows' mask DMA (flushed at next chunk top)
        u64 tb = km;
        while (tb) {
            int pos = __ffsll((long long)tb) - 1;
            tb &= tb - 1;
            u32 jk = (u32)__builtin_amdgcn_readlane((int)j, pos);
            if (lane < 40)                      // 40 lanes x 16B = full 640B row
                __builtin_amdgcn_global_load_lds(
                    (const as1u32*)((const u32*)(mask + (size_t)jk * NWORDS) + lane * 4),
                    (as3u32*)(u32*)&stag[pend * NWORDS], 16, 0, 0);
            ++pend;
            if (pend == NSTAG) {                // overflow flush (keep-heavy early chunks)
                __builtin_amdgcn_s_waitcnt(0);
                #pragma unroll
                for (int r = 0; r < NSTAG; ++r) {
                    S0 |= stag[r * NWORDS + lane];
                    if (lane < 16) S1 |= stag[r * NWORDS + 64 + lane];
                }
                pend = 0;
            }
        }
    }

    // release workers
    if (lane == 0) {
        __hip_atomic_store(&misc[1], 1u, __ATOMIC_RELEASE, __HIP_MEMORY_SCOPE_WORKGROUP);
        __hip_atomic_store(&misc[0], 1000000u, __ATOMIC_RELEASE, __HIP_MEMORY_SCOPE_WORKGROUP);
    }
}

extern "C" void kernel_launch(void* const* d_in, const int* in_sizes, int n_in,
                              void* d_out, int out_size, void* d_ws, size_t ws_size,
                              hipStream_t stream) {
    const float* boxes = (const float*)d_in[0];
    const float* cls   = (const float*)d_in[1];
    float* out = (float*)d_out;

    u32* bar  = (u32*)d_ws;                      // helper-done counter
    u64* mask = (u64*)((char*)d_ws + 1024);      // 3.20 MB

    hipMemsetAsync(bar, 0, 64, stream);
    nms_all<<<NSCAN + NHELP, BLOCK, 0, stream>>>(boxes, (const float4*)boxes, cls,
                                                 mask, bar, out);
}

// Round 10
// 140.630 us; speedup vs baseline: 2.2110x; 1.1813x over previous
//
#include <hip/hip_runtime.h>

#define N_ANCHORS 5000
#define N_CLASSES 80
#define OUT_COLS  84
#define MAX_BOXES 300
#define SCORE_THR 0.05f

#define SORT_PAD  5056
#define NB        4096
#define BLOCK     1024
#define IR        16                 // intra-matrix ring slots
#define KR        16                 // KS ring slots
#define DONEP     0x40000000

typedef unsigned long long u64;
typedef unsigned int u32;

#define WG __HIP_MEMORY_SCOPE_WORKGROUP

__device__ __forceinline__ float readlane_f(float v, int l) {
    return __int_as_float(__builtin_amdgcn_readlane(__float_as_int(v), l));
}
__device__ __forceinline__ u32 aload(u32* p) {
    return __hip_atomic_load(p, __ATOMIC_ACQUIRE, WG);
}
// monotone score->bucket map (load balance only, never exactness)
__device__ __forceinline__ int bucket_of(float s) {
    float u = sqrtf(s);
    int b = (int)((u - 0.2236f) * 5275.0f);
    return min(max(b, 0), NB - 1);
}
// IoU(a,b) > 0.5  <=>  3*inter > areaA+areaB   (union>0 always: areas >= 1)
__device__ __forceinline__ bool iou_gt(float4 a, float aa, float4 b, float ab) {
    float iw = fmaxf(fminf(a.z, b.z) - fmaxf(a.x, b.x), 0.0f);
    float ih = fmaxf(fminf(a.w, b.w) - fmaxf(a.y, b.y), 0.0f);
    return 3.0f * (iw * ih) > aa + ab;
}

// ================= 1) prep: coalesced out init + cls transpose =================
#define INIT_BLKS 1641               // ceil(5000*84/256)
#define TR_BX     157
#define TR_BY     3
#define TR_BLKS   (TR_BX * TR_BY)

__global__ __launch_bounds__(256) void prep(const float* __restrict__ boxes,
                                            const float* __restrict__ cls,
                                            float* __restrict__ clsT,
                                            float* __restrict__ out) {
    __shared__ float tile[32][33];
    int b = blockIdx.x;
    if (b < INIT_BLKS) {
        int i = b * 256 + threadIdx.x;
        if (i < N_ANCHORS * OUT_COLS) {
            int row = i / OUT_COLS, col = i - row * OUT_COLS;
            out[i] = (col < 4) ? boxes[row * 4 + col] : 0.0f;
        }
        return;
    }
    b -= INIT_BLKS;
    int bx_ = b % TR_BX, by_ = b / TR_BX;
    int j0 = bx_ * 32, c0 = by_ * 32;
    int tx = threadIdx.x & 31, ty = threadIdx.x >> 5;
    #pragma unroll
    for (int r = 0; r < 32; r += 8) {
        int j = j0 + ty + r, c = c0 + tx;
        tile[ty + r][tx] = (j < N_ANCHORS && c < N_CLASSES) ? cls[j * N_CLASSES + c] : 0.0f;
    }
    __syncthreads();
    #pragma unroll
    for (int r = 0; r < 32; r += 8) {
        int c = c0 + ty + r, j = j0 + tx;
        if (c < N_CLASSES && j < N_ANCHORS) clsT[(size_t)c * N_ANCHORS + j] = tile[tx][ty + r];
    }
}

// ================= 2) per-class: LDS sort + pipelined mask-free scan =================
__global__ __launch_bounds__(BLOCK, 1) void nms(const float* __restrict__ clsT,
                                                const float4* __restrict__ boxes4,
                                                float* __restrict__ out) {
    __shared__ u64 lk[SORT_PAD];        // 40448 B sorted keys (score desc, idx asc)
    __shared__ u32 hist[NB];            // 16384 B; aliased by Iring after sort
    __shared__ float4 kbox[MAX_BOXES + 4];
    __shared__ u64 KS[KR];              // suppressed-by-kept bitmaps
    __shared__ u32 flagI[IR], flagK[KR], KBa[KR];
    __shared__ u32 wtot[16];
    __shared__ u32 prog, kcnt;
    u64* Iring = (u64*)hist;            // IR*64*8 = 8192 <= 16384

    const int c = blockIdx.x;
    const int t = threadIdx.x;
    const int lane = t & 63;
    const int wv = t >> 6;

    // ---------- sort phase (all 16 waves) ----------
    const float4* cp4 = (const float4*)(clsT + (size_t)c * N_ANCHORS);
    u32 sb[8];
    #pragma unroll
    for (int m = 0; m < 2; ++m) {
        int vi = m * 1024 + t;
        float4 v = make_float4(0.f, 0.f, 0.f, 0.f);
        if (vi < N_ANCHORS / 4) v = cp4[vi];
        sb[m * 4 + 0] = (v.x > SCORE_THR) ? __float_as_uint(v.x) : 0u;
        sb[m * 4 + 1] = (v.y > SCORE_THR) ? __float_as_uint(v.y) : 0u;
        sb[m * 4 + 2] = (v.z > SCORE_THR) ? __float_as_uint(v.z) : 0u;
        sb[m * 4 + 3] = (v.w > SCORE_THR) ? __float_as_uint(v.w) : 0u;
    }
    for (int b = t; b < NB; b += BLOCK) hist[b] = 0u;
    if (t < IR) { flagI[t] = 0u; flagK[t] = 0u; }
    if (t == 0) { prog = 0u; kcnt = 0u; }
    __syncthreads();
    #pragma unroll
    for (int m = 0; m < 8; ++m)
        if (sb[m]) atomicAdd(&hist[bucket_of(__uint_as_float(sb[m]))], 1u);
    __syncthreads();

    const int hbase = t * 4;            // thread owns 4 buckets
    u32 vals[4]; u32 run = 0;
    #pragma unroll
    for (int k = 0; k < 4; ++k) { run += hist[hbase + k]; vals[k] = run; }
    u32 x = run;
    #pragma unroll
    for (int off = 1; off < 64; off <<= 1) { u32 y = __shfl_up(x, off); if (lane >= off) x += y; }
    if (lane == 63) wtot[wv] = x;
    __syncthreads();
    u32 woff = 0;
    for (int w = 0; w < wv; ++w) woff += wtot[w];
    const u32 exb = woff + x - run;
    #pragma unroll
    for (int k = 0; k < 4; ++k) hist[hbase + k] = exb + (k ? vals[k - 1] : 0u);
    __syncthreads();
    #pragma unroll
    for (int m = 0; m < 8; ++m) {
        if (sb[m]) {
            int j = ((m >> 2) * 1024 + t) * 4 + (m & 3);
            u32 pos = atomicAdd(&hist[bucket_of(__uint_as_float(sb[m]))], 1u);
            lk[pos] = ((u64)sb[m] << 32) | (u32)(~(u32)j);
        }
    }
    __syncthreads();                    // hist[b] now end of bucket b
    const int total = (int)hist[NB - 1];
    for (int v = total + t; v < SORT_PAD; v += BLOCK) lk[v] = 0ull;
    for (int b = hbase; b < hbase + 4; ++b) {       // exact sort within buckets
        int s0 = b ? (int)hist[b - 1] : 0;
        int e  = (int)hist[b];
        for (int i = s0 + 1; i < e; ++i) {
            u64 key = lk[i]; int q = i - 1;
            while (q >= s0 && lk[q] < key) { lk[q + 1] = lk[q]; --q; }
            lk[q + 1] = key;
        }
    }
    __syncthreads();                    // LAST barrier; roles diverge below
    const int nch = (total + 63) >> 6;

    if (wv >= 1 && wv <= 8) {
        // ======= intra workers: transposed 64x64 IoU matrices, ring-gated =======
        for (int j = wv - 1; j < nch; j += 8) {
            u32 p;
            for (;;) {
                p = aload(&prog);
                if ((int)p >= j - (IR - 1)) break;
                __builtin_amdgcn_s_sleep(2);
            }
            if (p >= DONEP) return;
            u64 e = lk[j * 64 + lane];
            u32 jj = e ? ~(u32)e : 0u;
            float4 bx = boxes4[jj];
            float ar = (bx.z - bx.x) * (bx.w - bx.y);
            u64 word = 0ull;            // bit q: entry q suppresses me (symmetric)
            #pragma unroll 16
            for (int q = 0; q < 64; ++q) {
                float4 o;
                o.x = readlane_f(bx.x, q); o.y = readlane_f(bx.y, q);
                o.z = readlane_f(bx.z, q); o.w = readlane_f(bx.w, q);
                float ao = (o.z - o.x) * (o.w - o.y);
                if (iou_gt(bx, ar, o, ao)) word |= (1ull << q);
            }
            Iring[(j & (IR - 1)) * 64 + lane] = word;
            if (lane == 0)
                __hip_atomic_store(&flagI[j & (IR - 1)], (u32)(j + 1), __ATOMIC_RELEASE, WG);
        }
        return;
    }
    if (wv >= 9) {
        // ======= sweep workers: suppressed-by-kept bitmap, two-stage =======
        for (int j = wv - 9; j < nch; j += 7) {
            u32 p;
            for (;;) {                  // stage A gate: prog >= j-6
                p = aload(&prog);
                if ((int)p >= j - 6) break;
                __builtin_amdgcn_s_sleep(2);
            }
            if (p >= DONEP) return;
            u64 e = lk[j * 64 + lane];
            u32 jj = e ? ~(u32)e : 0u;
            float4 bx = boxes4[jj];
            float ar = (bx.z - bx.x) * (bx.w - bx.y);
            u32 ka = aload(&kcnt);      // kept prefix known now (all from chunks < j)
            bool sup = false;
            for (u32 r = 0; r < ka; ++r) {
                float4 q = kbox[r];
                float aq = (q.z - q.x) * (q.w - q.y);
                if (iou_gt(bx, ar, q, aq)) sup = true;
            }
            for (;;) {                  // stage B gate: prog >= j-2
                p = aload(&prog);
                if ((int)p >= j - 2) break;
                __builtin_amdgcn_s_sleep(2);
            }
            u32 kb2 = (p >= DONEP) ? ka : aload(&kcnt);
            for (u32 r = ka; r < kb2; ++r) {
                float4 q = kbox[r];
                float aq = (q.z - q.x) * (q.w - q.y);
                if (iou_gt(bx, ar, q, aq)) sup = true;
            }
            u64 ksw = __ballot(sup);
            if (lane == 0) {
                KS[j & (KR - 1)] = ksw;
                KBa[j & (KR - 1)] = kb2;
                __hip_atomic_store(&flagK[j & (KR - 1)], (u32)(j + 1), __ATOMIC_RELEASE, WG);
            }
            if (p >= DONEP) return;
        }
        return;
    }

    // ======= wave 0: serial scan =======
    int kept = 0; u32 kcur = 0; bool capped = false;
    for (int k = 0; k < nch; ++k) {
        u64 key = lk[k * 64 + lane];
        bool valid = (key != 0ull);
        u32 j = valid ? ~(u32)key : 0u;
        float sc = __uint_as_float((u32)(key >> 32));
        float4 bx = boxes4[j];
        float ar = (bx.z - bx.x) * (bx.w - bx.y);

        while (aload(&flagK[k & (KR - 1)]) != (u32)(k + 1)) __builtin_amdgcn_s_sleep(1);
        u64 ks = KS[k & (KR - 1)];
        u32 kb = KBa[k & (KR - 1)];
        bool alive = valid && !((ks >> lane) & 1ull);
        for (u32 r = kb; r < kcur; ++r) {          // cover recent keeps (~last 2 chunks)
            float4 q = kbox[r];
            float aq = (q.z - q.x) * (q.w - q.y);
            if (iou_gt(bx, ar, q, aq)) alive = false;
        }

        while (aload(&flagI[k & (IR - 1)]) != (u32)(k + 1)) __builtin_amdgcn_s_sleep(1);
        u64 I = Iring[(k & (IR - 1)) * 64 + lane];

        u64 rem = __ballot(alive);
        u64 km = 0ull;
        while (rem) {                              // SALU keep chain
            int pos = __ffsll((long long)rem) - 1;
            km |= 1ull << pos;
            if (++kept == MAX_BOXES) { capped = true; break; }
            u32 lo = (u32)__builtin_amdgcn_readlane((int)(u32)I, pos);
            u32 hi = (u32)__builtin_amdgcn_readlane((int)(u32)(I >> 32), pos);
            rem &= ~(((u64)hi << 32) | (u64)lo);   // diag bit kills pos itself
        }
        int nk = __popcll(km);
        if ((km >> lane) & 1ull) {
            out[(size_t)j * OUT_COLS + 4 + c] = sc;
            kbox[kcur + __popcll(km & ((1ull << lane) - 1ull))] = bx;
        }
        kcur += (u32)nk;
        if (capped) break;
        if (lane == 0) {
            __hip_atomic_store(&kcnt, kcur, __ATOMIC_RELAXED, WG);
            __hip_atomic_store(&prog, (u32)(k + 1), __ATOMIC_RELEASE, WG);
        }
    }
    if (lane == 0) __hip_atomic_store(&prog, (u32)DONEP, __ATOMIC_RELEASE, WG);
}

extern "C" void kernel_launch(void* const* d_in, const int* in_sizes, int n_in,
                              void* d_out, int out_size, void* d_ws, size_t ws_size,
                              hipStream_t stream) {
    const float* boxes = (const float*)d_in[0];
    const float* cls   = (const float*)d_in[1];
    float* out = (float*)d_out;
    float* clsT = (float*)d_ws;                    // 1.60 MB scratch

    prep<<<INIT_BLKS + TR_BLKS, 256, 0, stream>>>(boxes, cls, clsT, out);
    nms<<<N_CLASSES, BLOCK, 0, stream>>>(clsT, (const float4*)boxes, out);
}